// Round 2
// baseline (1397.325 us; speedup 1.0000x reference)
//
#include <hip/hip_runtime.h>
#include <stdint.h>

#define KDIM 1792
#define MDIM 3136
#define MPAD 3200
#define NROWS 50176   // 16*3136
#define BM 128
#define BN 128
#define BK 64
#define NKT (KDIM / BK)     // 28
#define NTN (MPAD / BN)     // 25 col tiles
#define NTR (NROWS / BM)    // 392 row tiles
#define NSLOT (NTN * 2)     // 50 partial top-3 slots per row (one per 64-col half)
#define BIGV 1e30f

typedef __bf16 bf16;
typedef __attribute__((ext_vector_type(8))) __bf16 bf16x8;
typedef __attribute__((ext_vector_type(4))) float f32x4;

// global_load_lds address-space casts (LDS aperture is 4GB-aligned -> low 32 bits = LDS offset)
#define AS1(p) ((const __attribute__((address_space(1))) uint32_t*)(uintptr_t)(p))
#define AS3(p) ((__attribute__((address_space(3))) uint32_t*)(uint32_t)(uintptr_t)(p))

__device__ __forceinline__ uint16_t f2bf(float x) {
    union { float f; uint32_t u; } v; v.f = x;
    uint32_t r = (v.u + 0x7fffu + ((v.u >> 16) & 1u)) >> 16;  // RNE
    return (uint16_t)r;
}

// ---- prep 1: phi fp32 -> bf16, plus fp32 row sum-of-squares. One block per row. ----
__global__ void __launch_bounds__(256) prep_phi(const float* __restrict__ phi,
                                                uint16_t* __restrict__ phiB,
                                                float* __restrict__ rowsq) {
    const int r = blockIdx.x;
    const int t = threadIdx.x;
    const float4* src = (const float4*)(phi + (size_t)r * KDIM);
    ushort4* dst = (ushort4*)(phiB + (size_t)r * KDIM);
    float ss = 0.f;
#pragma unroll
    for (int i = 0; i < 2; ++i) {
        int idx = t + i * 256;            // 448 float4 per row
        if (idx < KDIM / 4) {
            float4 v = src[idx];
            ss += v.x * v.x + v.y * v.y + v.z * v.z + v.w * v.w;
            ushort4 o;
            o.x = f2bf(v.x); o.y = f2bf(v.y); o.z = f2bf(v.z); o.w = f2bf(v.w);
            dst[idx] = o;
        }
    }
#pragma unroll
    for (int off = 32; off > 0; off >>= 1) ss += __shfl_down(ss, off, 64);
    __shared__ float red[4];
    if ((t & 63) == 0) red[t >> 6] = ss;
    __syncthreads();
    if (t == 0) rowsq[r] = red[0] + red[1] + red[2] + red[3];
}

// ---- prep 2: C_bank [K,M] fp32 -> Bp [MPAD,K] bf16 (transpose), + column sumsq (atomic). ----
__global__ void __launch_bounds__(256) prep_bank(const float* __restrict__ Cb,
                                                 uint16_t* __restrict__ Bp,
                                                 float* __restrict__ colsq) {
    const int m0 = blockIdx.x * 64;   // 49 tiles (3136 = 49*64)
    const int k0 = blockIdx.y * 64;   // 28 tiles
    const int t = threadIdx.x;
    const int ci = t & 63, rg = t >> 6;
    __shared__ float tile[64][65];    // [k][m], +1 pad -> conflict-free transpose read
    __shared__ float ps[4][64];
    float ss = 0.f;
#pragma unroll
    for (int i = 0; i < 16; ++i) {
        int r = i * 4 + rg;
        float v = Cb[(size_t)(k0 + r) * MDIM + m0 + ci];
        tile[r][ci] = v;
        ss += v * v;
    }
    ps[rg][ci] = ss;
    __syncthreads();
    if (rg == 0) atomicAdd(&colsq[m0 + ci], ps[0][ci] + ps[1][ci] + ps[2][ci] + ps[3][ci]);
#pragma unroll
    for (int i = 0; i < 16; ++i) {
        int mr = i * 4 + rg;
        Bp[(size_t)(m0 + mr) * KDIM + k0 + ci] = f2bf(tile[ci][mr]);  // coalesced in k
    }
}

// ---- main: bf16 MFMA GEMM (A[NROWS,K] . Bp[MPAD,K]^T) with fused top-3-of-dist^2 epilogue ----
__global__ void __launch_bounds__(256) gemm_topk(const uint16_t* __restrict__ phiB,
                                                 const uint16_t* __restrict__ Bp,
                                                 const float* __restrict__ colsq,
                                                 float* __restrict__ ptop) {
    __shared__ __align__(16) bf16 As[BM * BK];
    __shared__ __align__(16) bf16 Bs[BN * BK];
    const int tn = blockIdx.x % NTN;
    const int tr = blockIdx.x / NTN;
    const int rowBase = tr * BM, colBase = tn * BN;
    const int t = threadIdx.x;
    const int lane = t & 63, w = t >> 6;
    const int wy = w >> 1, wx = w & 1;            // 2x2 waves, each 64x64
    const int laneM = lane & 15, laneK = lane >> 4;

    f32x4 zero = {0.f, 0.f, 0.f, 0.f};
    f32x4 acc[4][4];
#pragma unroll
    for (int i = 0; i < 4; ++i)
#pragma unroll
        for (int j = 0; j < 4; ++j) acc[i][j] = zero;

    // Staging geometry: 16B chunk c = t + i*256; LDS dest MUST be lane-contiguous (c*16B).
    // XOR-swizzle the k-chunk within each row (j_global = j_lds ^ (row&7)) to break the
    // 32-word row stride on b128 frag reads (m136: 2-way is free).
    const uint16_t* gAp[4];
    const uint16_t* gBp[4];
    bf16* lA[4];
    bf16* lB[4];
#pragma unroll
    for (int i = 0; i < 4; ++i) {
        int c = t + i * 256;
        int rr = c >> 3, ldsj = c & 7;
        int gj = ldsj ^ (rr & 7);
        gAp[i] = phiB + (size_t)(rowBase + rr) * KDIM + gj * 8;
        gBp[i] = Bp + (size_t)(colBase + rr) * KDIM + gj * 8;
        lA[i] = &As[c * 8];
        lB[i] = &Bs[c * 8];
    }
    // Fragment LDS element offsets (swizzle-aware)
    uint32_t aOff[2][4], bOff[2][4];
#pragma unroll
    for (int ks = 0; ks < 2; ++ks)
#pragma unroll
        for (int f = 0; f < 4; ++f) {
            int rowA = wy * 64 + f * 16 + laneM;
            int rowB = wx * 64 + f * 16 + laneM;
            int j = ks * 4 + laneK;
            aOff[ks][f] = (uint32_t)(rowA * 8 + (j ^ (rowA & 7))) * 8;
            bOff[ks][f] = (uint32_t)(rowB * 8 + (j ^ (rowB & 7))) * 8;
        }

    for (int kt = 0; kt < NKT; ++kt) {
        const int kk = kt * BK;
#pragma unroll
        for (int i = 0; i < 4; ++i) {
            __builtin_amdgcn_global_load_lds(AS1(gAp[i] + kk), AS3(lA[i]), 16, 0, 0);
            __builtin_amdgcn_global_load_lds(AS1(gBp[i] + kk), AS3(lB[i]), 16, 0, 0);
        }
        __syncthreads();
#pragma unroll
        for (int ks = 0; ks < 2; ++ks) {
            bf16x8 af[4], bfr[4];
#pragma unroll
            for (int f = 0; f < 4; ++f) af[f] = *(const bf16x8*)&As[aOff[ks][f]];
#pragma unroll
            for (int f = 0; f < 4; ++f) bfr[f] = *(const bf16x8*)&Bs[bOff[ks][f]];
#pragma unroll
            for (int fy = 0; fy < 4; ++fy)
#pragma unroll
                for (int fx = 0; fx < 4; ++fx)
                    acc[fy][fx] = __builtin_amdgcn_mfma_f32_16x16x32_bf16(af[fy], bfr[fx], acc[fy][fx], 0, 0, 0);
        }
        __syncthreads();
    }

    // Epilogue: v = colsq - 2*dot (same ordering as dist^2; rowsq added at merge).
    // C/D layout (m89-verified): col = lane&15, row = (lane>>4)*4 + reg.
    float cq[4];
#pragma unroll
    for (int fx = 0; fx < 4; ++fx) {
        int col = colBase + wx * 64 + fx * 16 + laneM;
        cq[fx] = (col < MDIM) ? colsq[col] : BIGV;  // mask padding cols
    }
#pragma unroll
    for (int fy = 0; fy < 4; ++fy) {
#pragma unroll
        for (int reg = 0; reg < 4; ++reg) {
            float v0 = fmaf(-2.f, acc[fy][0][reg], cq[0]);
            float v1 = fmaf(-2.f, acc[fy][1][reg], cq[1]);
            float v2 = fmaf(-2.f, acc[fy][2][reg], cq[2]);
            float v3 = fmaf(-2.f, acc[fy][3][reg], cq[3]);
            // sort4, keep 3 smallest
            float lo01 = fminf(v0, v1), hi01 = fmaxf(v0, v1);
            float lo23 = fminf(v2, v3), hi23 = fmaxf(v2, v3);
            float a0 = fminf(lo01, lo23);
            float mid = fmaxf(lo01, lo23), bb = fminf(hi01, hi23);
            float a1 = fminf(mid, bb), a2 = fmaxf(mid, bb);
            // butterfly merge across the 16 lanes sharing this row group (masks 1,2,4,8)
#pragma unroll
            for (int msk = 1; msk <= 8; msk <<= 1) {
                float b0 = __shfl_xor(a0, msk, 64);
                float b1 = __shfl_xor(a1, msk, 64);
                float b2 = __shfl_xor(a2, msk, 64);
                float mn0 = fminf(a0, b0), mx0 = fmaxf(a0, b0);
                float mn1 = fminf(a1, b1), mx1 = fmaxf(a1, b1);
                float mn2 = fminf(a2, b2);
                a0 = mn0;
                float n1 = fminf(mx0, mn1);
                a2 = fminf(fmaxf(mx0, mn1), fminf(mx1, mn2));
                a1 = n1;
            }
            if (laneM == 0) {
                int row = rowBase + wy * 64 + fy * 16 + laneK * 4 + reg;
                // RACE FIX (R1): wx=0 and wx=1 waves cover different column halves of the
                // same rows -> each gets its own slot (tn*2+wx), merged in merge_score.
                float* o = ptop + ((size_t)(tn * 2 + wx) * NROWS + row) * 3;
                o[0] = a0; o[1] = a1; o[2] = a2;
            }
        }
    }
}

// ---- merge 50 partial top-3 per row -> softmin score ----
__global__ void __launch_bounds__(256) merge_score(const float* __restrict__ ptop,
                                                   const float* __restrict__ rowsq,
                                                   float* __restrict__ out) {
    int r = blockIdx.x * 256 + threadIdx.x;
    if (r >= NROWS) return;
    float t0 = BIGV, t1 = BIGV, t2 = BIGV;
    for (int s = 0; s < NSLOT; ++s) {
        const float* p = ptop + ((size_t)s * NROWS + r) * 3;
#pragma unroll
        for (int j = 0; j < 3; ++j) {
            float x = p[j];
            float n0 = fminf(t0, x);
            float n1 = fminf(t1, fmaxf(t0, x));
            float n2 = fminf(t2, fmaxf(t1, x));
            t0 = n0; t1 = n1; t2 = n2;
        }
    }
    float rq = rowsq[r];
    float d0 = sqrtf(fmaxf(rq + t0, 0.f));
    float d1 = sqrtf(fmaxf(rq + t1, 0.f));
    float d2 = sqrtf(fmaxf(rq + t2, 0.f));
    // softmax(-d)[0] * d0, stable since d0 <= d1,d2
    float w0 = 1.f / (1.f + __expf(d0 - d1) + __expf(d0 - d2));
    out[r] = w0 * d0;
}

extern "C" void kernel_launch(void* const* d_in, const int* in_sizes, int n_in,
                              void* d_out, int out_size, void* d_ws, size_t ws_size,
                              hipStream_t stream) {
    const float* phi = (const float*)d_in[0];   // [16,3136,1792] fp32
    const float* Cb  = (const float*)d_in[1];   // [1792,3136] fp32
    float* out = (float*)d_out;                 // [16,3136,1] fp32

    char* ws = (char*)d_ws;
    size_t o = 0;
    uint16_t* phiB = (uint16_t*)(ws + o); o += (size_t)NROWS * KDIM * 2;   // 179.8 MB
    uint16_t* Bpw  = (uint16_t*)(ws + o); o += (size_t)MPAD * KDIM * 2;    // 11.5 MB
    float* rowsq   = (float*)(ws + o);    o += (size_t)NROWS * 4;
    float* colsq   = (float*)(ws + o);    o += (size_t)MPAD * 4;
    float* ptop    = (float*)(ws + o);    o += (size_t)NSLOT * NROWS * 3 * 4; // 30.1 MB

    hipMemsetAsync(Bpw, 0, (size_t)MPAD * KDIM * 2, stream);   // zero padding rows 3136..3199
    hipMemsetAsync(colsq, 0, (size_t)MPAD * 4, stream);        // atomic accumulation base
    prep_phi<<<NROWS, 256, 0, stream>>>(phi, phiB, rowsq);
    prep_bank<<<dim3(MDIM / 64, KDIM / 64), 256, 0, stream>>>(Cb, Bpw, colsq);
    gemm_topk<<<NTR * NTN, 256, 0, stream>>>(phiB, Bpw, colsq, ptop);
    merge_score<<<(NROWS + 255) / 256, 256, 0, stream>>>(ptop, rowsq, out);
}